// Round 8
// baseline (30.979 us; speedup 1.0000x reference)
//
#include <hip/hip_runtime.h>
#include <math.h>

// LogicConv2d, single fused kernel, 2 batches per lane.
//
// Block = 256 threads (4 waves) <-> 128 batches; lane <-> batches {lane, lane+64}.
//  - Waves 0-2 stage the 128x81 input tile into LDS (coalesced float4).
//  - Wave 3 concurrently builds the weight table in LDS: softmax(sel_a),
//    softmax(sel_b), 16-way soft-logic mix collapsed to
//    out = Cab*ab + Ca*a + Cb*b + C0.   tab[81][24] = sa[9] sb[9] C[4] pad.
//  - Compute: wave w (w<3) owns units 27w..27w+26 == patch-row w; BOTH
//    batches' 27 inputs hoisted to registers; weights via wave-uniform
//    ds_read_b128 broadcast (the dominant LDS cost, now amortized over
//    128 batches instead of 64); fully unrolled.
//  - Read-slice == write-slice per wave -> results overwrite the tile in
//    place; one barrier each side of compute; coalesced float4 writeback.
//
// LDS = 41472 + 7776 = 49.2 KB -> 3 blocks/CU; grid 1024 -> 1.33 rounds.

#define NB      131072
#define NUNITS  81
#define BPB     128           // batches per block (2 per lane)
#define THREADS 256
#define NBLK    (NB / BPB)    // 1024
#define REC     24            // floats per unit record (96 B, 16B-aligned)
#define CHUNKS  (BPB * 81 / 4) // 2592 float4 per tile

__global__ __launch_bounds__(THREADS)
void logic_fused_kernel(const float* __restrict__ x,
                        const float* __restrict__ sa_logits,
                        const float* __restrict__ sb_logits,
                        const float* __restrict__ op_logits,
                        float* __restrict__ out)
{
    __shared__ float s_tile[BPB * 81];     // 41472 B
    __shared__ float s_tab[NUNITS * REC];  //  7776 B

    const int tid   = threadIdx.x;
    const int lane  = tid & 63;
    const int wavei = __builtin_amdgcn_readfirstlane(tid >> 6);
    const size_t b0 = (size_t)blockIdx.x * BPB;

    if (wavei < 3) {
        // ---- staging by waves 0-2: 2592 chunks / 192 threads = 13.5 ----
        const float4* gsrc = (const float4*)(x + b0 * 81);
        float4* s4 = (float4*)s_tile;
        const int t3 = wavei * 64 + lane;          // 0..191
        #pragma unroll
        for (int k = 0; k < 14; ++k) {
            int j = t3 + k * 192;
            if (j < CHUNKS) s4[j] = gsrc[j];
        }
    } else {
        // ---- wave 3: build weight table (hidden under staging) ----
        for (int u = lane; u < NUNITS; u += 64) {
            float v[9], m = -1e30f;
            #pragma unroll
            for (int i = 0; i < 9; ++i) { v[i] = sa_logits[u * 9 + i]; m = fmaxf(m, v[i]); }
            float s = 0.f;
            #pragma unroll
            for (int i = 0; i < 9; ++i) { v[i] = expf(v[i] - m); s += v[i]; }
            const float r = 1.f / s;
            #pragma unroll
            for (int i = 0; i < 9; ++i) s_tab[u * REC + i] = v[i] * r;
        }
        for (int u = lane; u < NUNITS; u += 64) {
            float v[9], m = -1e30f;
            #pragma unroll
            for (int i = 0; i < 9; ++i) { v[i] = sb_logits[u * 9 + i]; m = fmaxf(m, v[i]); }
            float s = 0.f;
            #pragma unroll
            for (int i = 0; i < 9; ++i) { v[i] = expf(v[i] - m); s += v[i]; }
            const float r = 1.f / s;
            #pragma unroll
            for (int i = 0; i < 9; ++i) s_tab[u * REC + 9 + i] = v[i] * r;
        }
        for (int u = lane; u < NUNITS; u += 64) {
            float v[16], m = -1e30f;
            #pragma unroll
            for (int i = 0; i < 16; ++i) { v[i] = op_logits[u * 16 + i]; m = fmaxf(m, v[i]); }
            float s = 0.f;
            #pragma unroll
            for (int i = 0; i < 16; ++i) { v[i] = expf(v[i] - m); s += v[i]; }
            const float r = 1.f / s;
            #pragma unroll
            for (int i = 0; i < 16; ++i) v[i] *= r;
            const float cab = v[1] - v[2] - v[4] - 2.f*v[6] - v[7] + v[8] + 2.f*v[9]
                            + v[11] + v[13] - v[14];
            const float ca  = v[2] + v[3] + v[6] + v[7] - v[8] - v[9] - v[12] - v[13];
            const float cb  = v[4] + v[5] + v[6] + v[7] - v[8] - v[9] - v[10] - v[11];
            const float c0  = v[8] + v[9] + v[10] + v[11] + v[12] + v[13] + v[14] + v[15];
            s_tab[u * REC + 18] = cab;
            s_tab[u * REC + 19] = ca;
            s_tab[u * REC + 20] = cb;
            s_tab[u * REC + 21] = c0;
        }
    }

    __syncthreads();

    // ---- compute: wave w (w<3) owns units 27w..27w+26, 2 batches/lane ----
    if (wavei < 3) {
        float* my0 = s_tile + lane * 81        + wavei * 27;  // batch lane
        float* my1 = s_tile + (lane + 64) * 81 + wavei * 27;  // batch lane+64

        float in0[27], in1[27];
        #pragma unroll
        for (int j = 0; j < 27; ++j) in0[j] = my0[j];
        #pragma unroll
        for (int j = 0; j < 27; ++j) in1[j] = my1[j];

        const float* __restrict__ wt = s_tab + wavei * 27 * REC;  // uniform base

        #pragma unroll
        for (int j = 0; j < 27; ++j) {                  // unit u = 27*wavei + j
            const int q = j / 9;                        // patch col within row
            const float* __restrict__ wr = wt + j * REC;  // broadcast, imm offs
            float a0 = 0.f, b0v = 0.f, a1 = 0.f, b1v = 0.f;
            #pragma unroll
            for (int i = 0; i < 9; ++i) {
                const int idx = q * 3 + (i / 3) * 9 + (i % 3);
                const float wa = wr[i], wb = wr[9 + i];
                a0  = fmaf(in0[idx], wa, a0);
                b0v = fmaf(in0[idx], wb, b0v);
                a1  = fmaf(in1[idx], wa, a1);
                b1v = fmaf(in1[idx], wb, b1v);
            }
            const float cab = wr[18], ca = wr[19], cb = wr[20], c0 = wr[21];
            my0[j] = fmaf(cab, a0 * b0v, fmaf(ca, a0, fmaf(cb, b0v, c0)));
            my1[j] = fmaf(cab, a1 * b1v, fmaf(ca, a1, fmaf(cb, b1v, c0)));
        }
    }

    __syncthreads();

    // ---- coalesced writeback, all 4 waves: 2592 / 256 = 10.125 ----
    {
        const float4* s4 = (const float4*)s_tile;
        float4* gdst = (float4*)(out + b0 * 81);
        #pragma unroll
        for (int k = 0; k < 11; ++k) {
            int j = tid + k * THREADS;
            if (j < CHUNKS) gdst[j] = s4[j];
        }
    }
}

extern "C" void kernel_launch(void* const* d_in, const int* in_sizes, int n_in,
                              void* d_out, int out_size, void* d_ws, size_t ws_size,
                              hipStream_t stream)
{
    const float* x  = (const float*)d_in[0];
    const float* sa = (const float*)d_in[1];
    const float* sb = (const float*)d_in[2];
    const float* op = (const float*)d_in[3];
    float* outp = (float*)d_out;

    logic_fused_kernel<<<NBLK, THREADS, 0, stream>>>(x, sa, sb, op, outp);
}

// Round 9
// 30.101 us; speedup vs baseline: 1.0292x; 1.0292x over previous
//
#include <hip/hip_runtime.h>
#include <math.h>

// LogicConv2d, prep + max-occupancy main.
//
// prep (1 block): softmax(sel_a), softmax(sel_b), collapse 16-way mix to
//   out = Cab*ab + Ca*a + Cb*b + C0. tab[81][24] floats in d_ws, layout
//   readable as 6 aligned float4s per unit:
//   q0=sa[0:4] q1=sa[4:8] q2={sa8,sb0,sb1,sb2} q3=sb[3:7] q4={sb7,sb8,Cab,Ca}
//   q5={Cb,C0,-,-}.
//
// main: 2048 blocks x 256 threads <-> 64 batches; lane <-> batch.
//   LDS = one 20.7 KB tile only -> 7 blocks/CU (28 waves) — occupancy is
//   the lever this round (R1..R8 evidence: all pipes idle, occupancy tracks
//   perf). Staging via global_load_lds DMA (no VGPR round-trip). Compute:
//   wave w<3 owns units 27w..27w+26 == patch-row w; 27 inputs hoisted to
//   registers; weights via wave-uniform float4 loads from d_ws (L2-hot
//   broadcast); fully unrolled; results overwrite the tile in place.

#define NB      131072
#define NUNITS  81
#define BPB     64             // batches per block
#define THREADS 256
#define NBLK    (NB / BPB)     // 2048
#define REC     24             // floats per unit record (96 B)
#define CHUNKS  (BPB * 81 / 4) // 1296 float4 per tile

typedef __attribute__((address_space(1))) const void GAS;
typedef __attribute__((address_space(3))) void LAS;

__global__ __launch_bounds__(256)
void logic_prep_kernel(const float* __restrict__ sa_logits,
                       const float* __restrict__ sb_logits,
                       const float* __restrict__ op_logits,
                       float* __restrict__ tab)
{
    const int tid = threadIdx.x;
    if (tid < 81) {
        const int u = tid;
        float v[9], m = -1e30f;
        #pragma unroll
        for (int i = 0; i < 9; ++i) { v[i] = sa_logits[u * 9 + i]; m = fmaxf(m, v[i]); }
        float s = 0.f;
        #pragma unroll
        for (int i = 0; i < 9; ++i) { v[i] = expf(v[i] - m); s += v[i]; }
        const float r = 1.f / s;
        #pragma unroll
        for (int i = 0; i < 9; ++i) tab[u * REC + i] = v[i] * r;
    } else if (tid < 162) {
        const int u = tid - 81;
        float v[9], m = -1e30f;
        #pragma unroll
        for (int i = 0; i < 9; ++i) { v[i] = sb_logits[u * 9 + i]; m = fmaxf(m, v[i]); }
        float s = 0.f;
        #pragma unroll
        for (int i = 0; i < 9; ++i) { v[i] = expf(v[i] - m); s += v[i]; }
        const float r = 1.f / s;
        #pragma unroll
        for (int i = 0; i < 9; ++i) tab[u * REC + 9 + i] = v[i] * r;
    } else if (tid < 243) {
        const int u = tid - 162;
        float v[16], m = -1e30f;
        #pragma unroll
        for (int i = 0; i < 16; ++i) { v[i] = op_logits[u * 16 + i]; m = fmaxf(m, v[i]); }
        float s = 0.f;
        #pragma unroll
        for (int i = 0; i < 16; ++i) { v[i] = expf(v[i] - m); s += v[i]; }
        const float r = 1.f / s;
        #pragma unroll
        for (int i = 0; i < 16; ++i) v[i] *= r;
        const float cab = v[1] - v[2] - v[4] - 2.f*v[6] - v[7] + v[8] + 2.f*v[9]
                        + v[11] + v[13] - v[14];
        const float ca  = v[2] + v[3] + v[6] + v[7] - v[8] - v[9] - v[12] - v[13];
        const float cb  = v[4] + v[5] + v[6] + v[7] - v[8] - v[9] - v[10] - v[11];
        const float c0  = v[8] + v[9] + v[10] + v[11] + v[12] + v[13] + v[14] + v[15];
        tab[u * REC + 18] = cab;
        tab[u * REC + 19] = ca;
        tab[u * REC + 20] = cb;
        tab[u * REC + 21] = c0;
    }
}

__global__ __launch_bounds__(THREADS, 7)
void logic_main_kernel(const float* __restrict__ x,
                       const float* __restrict__ tab,
                       float* __restrict__ out)
{
    __shared__ float s_tile[BPB * 81];     // 20736 B — the only LDS

    const int tid   = threadIdx.x;
    const int lane  = tid & 63;
    const int wavei = __builtin_amdgcn_readfirstlane(tid >> 6);
    const size_t b0 = (size_t)blockIdx.x * BPB;

    // ---- stage input tile via global->LDS DMA (16 B / lane / instr) ----
    {
        const float4* gsrc = (const float4*)(x + b0 * 81);
        #pragma unroll
        for (int k = 0; k < 6; ++k) {
            const int j = tid + k * THREADS;            // this lane's chunk
            if (j < CHUNKS) {
                // wave-uniform LDS base: chunk (k*256 + wave*64); lane offset
                // is applied by hardware as lane*16.
                float* lbase = s_tile + (size_t)(k * THREADS + wavei * 64) * 4;
                __builtin_amdgcn_global_load_lds((GAS*)(gsrc + j), (LAS*)lbase,
                                                 16, 0, 0);
            }
        }
    }
    __syncthreads();

    // ---- compute: wave w (w<3) owns units 27w..27w+26 (== patch-row w) ----
    if (wavei < 3) {
        float* my = s_tile + lane * 81 + wavei * 27;    // read == write slice

        float in[27];                                    // img rows 3w..3w+2
        #pragma unroll
        for (int j = 0; j < 27; ++j) in[j] = my[j];

        const float4* __restrict__ wt4 =
            (const float4*)(tab + (size_t)wavei * 27 * REC);  // uniform base

        #pragma unroll
        for (int j = 0; j < 27; ++j) {                   // unit u = 27*wavei+j
            const int q = j / 9;                         // patch col within row
            const float4 q0 = wt4[j * 6 + 0];
            const float4 q1 = wt4[j * 6 + 1];
            const float4 q2 = wt4[j * 6 + 2];
            const float4 q3 = wt4[j * 6 + 3];
            const float4 q4 = wt4[j * 6 + 4];
            const float4 q5 = wt4[j * 6 + 5];
            const float wa[9] = { q0.x, q0.y, q0.z, q0.w, q1.x, q1.y, q1.z, q1.w, q2.x };
            const float wb[9] = { q2.y, q2.z, q2.w, q3.x, q3.y, q3.z, q3.w, q4.x, q4.y };
            float a = 0.f, b = 0.f;
            #pragma unroll
            for (int i = 0; i < 9; ++i) {
                const float xi = in[q * 3 + (i / 3) * 9 + (i % 3)];
                a = fmaf(xi, wa[i], a);
                b = fmaf(xi, wb[i], b);
            }
            // q4.z=Cab q4.w=Ca q5.x=Cb q5.y=C0
            my[j] = fmaf(q4.z, a * b, fmaf(q4.w, a, fmaf(q5.x, b, q5.y)));
        }
    }

    __syncthreads();

    // ---- coalesced writeback, all 4 waves ----
    {
        const float4* s4 = (const float4*)s_tile;
        float4* gdst = (float4*)(out + b0 * 81);
        #pragma unroll
        for (int k = 0; k < 6; ++k) {
            const int j = tid + k * THREADS;
            if (j < CHUNKS) gdst[j] = s4[j];
        }
    }
}

extern "C" void kernel_launch(void* const* d_in, const int* in_sizes, int n_in,
                              void* d_out, int out_size, void* d_ws, size_t ws_size,
                              hipStream_t stream)
{
    const float* x  = (const float*)d_in[0];
    const float* sa = (const float*)d_in[1];
    const float* sb = (const float*)d_in[2];
    const float* op = (const float*)d_in[3];
    float* tab  = (float*)d_ws;             // 81*24*4 = 7776 B
    float* outp = (float*)d_out;

    logic_prep_kernel<<<1, 256, 0, stream>>>(sa, sb, op, tab);
    logic_main_kernel<<<NBLK, THREADS, 0, stream>>>(x, tab, outp);
}